// Round 16
// baseline (2416.188 us; speedup 1.0000x reference)
//
#include <hip/hip_runtime.h>
#include <math.h>

// PhaseRefinement fused kernel, v16 = v15 with the occupancy handbrake
// released: __launch_bounds__(512, 8) -> 4 blocks/CU (was (512,4) -> 2).
// R15 post-mortem: occ 43.7% was MY launch bound, not a resource limit --
// second launch_bounds arg is waves/SIMD, so 4 -> k=2 blocks/CU = 50% cap.
// Resources allow 4 blocks: VGPR=64 (the 8-wave/SIMD tier edge, m69),
// LDS 34.3KB x 4 = 137KB < 160KB. Doubling resident waves covers the
// remaining stalls (barrier vmcnt drains, L1 returns, HBM latency) with
// TLP -- the lever every structural attempt (R4/R6/R7/R9) was fighting
// for via scheduling instead.
// Structure (proven in R15, best=380us kernel): x staged once per block
// into LDS (separate 128 B/cyc port) via global_load_lds, double-buffered
// 2-chunk groups, 9 barriers; W via L1 (4 loads/wave/chunk); stats from
// staged x; parallel scalar tail; column-sliced phase B.
//
// out = x + LN(c*x)*gamma + beta; LN(c*x) collapses to
//   normed = gamma*(alpha*x - alpha*mu) + beta,
//   alpha = c*rsqrt(c^2*var + 1e-5), mu/var = plain row stats of x.

constexpr int Dh     = 4096;
constexpr int Ph     = 16;
constexpr int NPL    = 32;
constexpr int CHUNK  = 256;           // 64 lanes * 4 floats
constexpr int GCH    = 2;             // chunks per group (512 cols)
constexpr int NGRP   = Dh / (CHUNK * GCH);   // 8
constexpr int RPB    = 8;             // rows per block
constexpr int NW     = 8;             // waves per block
constexpr int PPW    = NPL / NW;      // 4 planes per wave
constexpr int BLOCK  = 64 * NW;       // 512

__device__ __forceinline__ void stage_chunk(const float* src, float* ldsdst) {
    __builtin_amdgcn_global_load_lds(
        (const __attribute__((address_space(1))) void*)src,
        (__attribute__((address_space(3))) void*)ldsdst, 16, 0, 0);
}

__global__ __launch_bounds__(BLOCK, 8)
void phase_fused(const float* __restrict__ x,
                 const float* __restrict__ Wr,
                 const float* __restrict__ br,
                 const float* __restrict__ Wo,
                 const float* __restrict__ bo,
                 const float* __restrict__ gamma,
                 const float* __restrict__ beta,
                 float* __restrict__ out)
{
    __shared__ float x_lds[2][GCH][RPB][CHUNK];   // 32 KB double buffer
    __shared__ float dots_lds[RPB][NPL];
    __shared__ float stats_lds[RPB][2];
    __shared__ float scale_lds[RPB][2];

    const int t    = threadIdx.x;
    const int wv   = t >> 6;
    const int lane = t & 63;
    const size_t rowbase = (size_t)blockIdx.x * RPB;

    // Per-wave W pointers (lane offset folded in).
    const float* wrow[PPW];
#pragma unroll
    for (int p = 0; p < PPW; ++p) {
        const int q = wv * PPW + p;
        wrow[p] = ((q < Ph) ? (Wr + (size_t)q * Dh) : (Wo + (size_t)(q - Ph) * Dh))
                  + lane * 4;
    }
    // Wave wv stages row wv; global src per-lane, LDS dst wave-uniform linear.
    const float* xsrc = x + (rowbase + wv) * (size_t)Dh + lane * 4;

    float acc[RPB][PPW];
#pragma unroll
    for (int r = 0; r < RPB; ++r)
#pragma unroll
        for (int p = 0; p < PPW; ++p) acc[r][p] = 0.f;
    float sx = 0.f, sxx = 0.f;

    // Stage one 512-col group (2 chunks) of this wave's row into buf.
    auto stage_group = [&](int g, int buf) {
#pragma unroll
        for (int k = 0; k < GCH; ++k)
            stage_chunk(xsrc + (size_t)(g * GCH + k) * CHUNK,
                        &x_lds[buf][k][wv][0]);
    };

    // Compute one group from buf (const buf at every call site).
    auto compute_group = [&](int g, int buf) {
#pragma unroll 1
        for (int k = 0; k < GCH; ++k) {
            const int off = (g * GCH + k) * CHUNK;
            float4 w4[PPW];
#pragma unroll
            for (int p = 0; p < PPW; ++p)
                w4[p] = *(const float4*)(wrow[p] + off);
            float4 x4[RPB];
#pragma unroll
            for (int r = 0; r < RPB; ++r)
                x4[r] = *(const float4*)(&x_lds[buf][k][r][lane * 4]);

#pragma unroll
            for (int r = 0; r < RPB; ++r) {
                if (r == wv) {   // wave-uniform; static indices
                    sx  += x4[r].x + x4[r].y + x4[r].z + x4[r].w;
                    sxx += x4[r].x*x4[r].x + x4[r].y*x4[r].y
                         + x4[r].z*x4[r].z + x4[r].w*x4[r].w;
                }
#pragma unroll
                for (int p = 0; p < PPW; ++p)
                    acc[r][p] += x4[r].x*w4[p].x + x4[r].y*w4[p].y
                               + x4[r].z*w4[p].z + x4[r].w*w4[p].w;
            }
        }
    };

    // Software pipeline, 9 barriers. compute(g) reads buf g&1 while
    // stage(g+1) fills the other; the vmcnt(0) drain at each barrier is
    // covered by group compute + 3 co-resident blocks' progress.
    stage_group(0, 0);
    __syncthreads();
    stage_group(1, 1); compute_group(0, 0);
    __syncthreads();
    stage_group(2, 0); compute_group(1, 1);
    __syncthreads();
    stage_group(3, 1); compute_group(2, 0);
    __syncthreads();
    stage_group(4, 0); compute_group(3, 1);
    __syncthreads();
    stage_group(5, 1); compute_group(4, 0);
    __syncthreads();
    stage_group(6, 0); compute_group(5, 1);
    __syncthreads();
    stage_group(7, 1); compute_group(6, 0);
    __syncthreads();
    compute_group(7, 1);

    // Butterfly-reduce accumulators across the 64 lanes.
#pragma unroll
    for (int r = 0; r < RPB; ++r)
#pragma unroll
        for (int p = 0; p < PPW; ++p) {
            float v = acc[r][p];
#pragma unroll
            for (int m = 1; m < 64; m <<= 1) v += __shfl_xor(v, m, 64);
            if (lane == 0) dots_lds[r][wv * PPW + p] = v;
        }
#pragma unroll
    for (int m = 1; m < 64; m <<= 1) {
        sx  += __shfl_xor(sx, m, 64);
        sxx += __shfl_xor(sxx, m, 64);
    }
    if (lane == 0) { stats_lds[wv][0] = sx; stats_lds[wv][1] = sxx; }
    __syncthreads();

    // Scalar phase, parallel over (row, plane): 128 threads, 16-lane reduce.
    if (t < RPB * Ph) {
        const int r = t >> 4, p = t & 15;
        float d1 = dots_lds[r][p]      + br[p];
        float d2 = dots_lds[r][Ph + p] + bo[p];
        float cd = cosf((tanhf(d1) - tanhf(d2)) * 3.14159265358979323846f);
#pragma unroll
        for (int m = 1; m < 16; m <<= 1) cd += __shfl_xor(cd, m, 16);
        if (p == 0) {
            float s    = cd;
            float gain = log1pf(expf(s * (1.f / Ph) + 0.5f));  // softplus
            float cm   = s * gain * (1.f / Ph);
            float mu   = stats_lds[r][0] * (1.f / Dh);
            float var  = stats_lds[r][1] * (1.f / Dh) - mu * mu;
            var = fmaxf(var, 0.f);
            float rstd  = rsqrtf(cm * cm * var + 1e-5f);
            float alpha = cm * rstd;
            scale_lds[r][0] = alpha;
            scale_lds[r][1] = alpha * mu;
        }
    }
    __syncthreads();

    // Phase B, column-sliced: wave wv owns cols [wv*512, wv*512+512);
    // gamma/beta loaded ONCE per wave, reused across all 8 rows. x re-read
    // is L2-hot (FETCH_SIZE ~= x-once at HBM every round).
    {
        const int col0 = wv * 512 + lane * 4;
        const float4 g4a = *(const float4*)(gamma + col0);
        const float4 g4b = *(const float4*)(gamma + col0 + 256);
        const float4 b4a = *(const float4*)(beta  + col0);
        const float4 b4b = *(const float4*)(beta  + col0 + 256);
#pragma unroll
        for (int r = 0; r < RPB; ++r) {
            const float alpha = scale_lds[r][0];
            const float am    = scale_lds[r][1];
            const float* xr  = x   + (rowbase + r) * (size_t)Dh;
            float*       orw = out + (rowbase + r) * (size_t)Dh;
            float4 xa = *(const float4*)(xr + col0);
            float4 xb = *(const float4*)(xr + col0 + 256);
            float4 oa, ob;
            oa.x = xa.x + g4a.x * (alpha * xa.x - am) + b4a.x;
            oa.y = xa.y + g4a.y * (alpha * xa.y - am) + b4a.y;
            oa.z = xa.z + g4a.z * (alpha * xa.z - am) + b4a.z;
            oa.w = xa.w + g4a.w * (alpha * xa.w - am) + b4a.w;
            ob.x = xb.x + g4b.x * (alpha * xb.x - am) + b4b.x;
            ob.y = xb.y + g4b.y * (alpha * xb.y - am) + b4b.y;
            ob.z = xb.z + g4b.z * (alpha * xb.z - am) + b4b.z;
            ob.w = xb.w + g4b.w * (alpha * xb.w - am) + b4b.w;
            *(float4*)(orw + col0)       = oa;
            *(float4*)(orw + col0 + 256) = ob;
        }
    }
}

extern "C" void kernel_launch(void* const* d_in, const int* in_sizes, int n_in,
                              void* d_out, int out_size, void* d_ws, size_t ws_size,
                              hipStream_t stream)
{
    const float* x     = (const float*)d_in[0];
    const float* Wr    = (const float*)d_in[1];
    const float* br    = (const float*)d_in[2];
    const float* Wo    = (const float*)d_in[3];
    const float* bo    = (const float*)d_in[4];
    const float* gamma = (const float*)d_in[5];
    const float* beta  = (const float*)d_in[6];
    float* out = (float*)d_out;

    const int B = in_sizes[0] / Dh;       // 32768
    dim3 grid(B / RPB);                   // 4096 blocks
    phase_fused<<<grid, BLOCK, 0, stream>>>(x, Wr, br, Wo, bo, gamma, beta, out);
}

// Round 17
// 1637.483 us; speedup vs baseline: 1.4755x; 1.4755x over previous
//
#include <hip/hip_runtime.h>
#include <math.h>

// PhaseRefinement fused kernel, v17 = v15 at the 3-blocks/CU tier.
// R16 lesson: (512,8) forced a 32-VGPR granule -> acc spilled (FETCH 4.1GB/
// WRITE 6.3GB scratch, 2.4ms at 88% occ). Occupancy without registers is
// worthless. (512,6) -> ~80-84 VGPR budget: holds the proven 64-VGPR body
// with zero spill, allows 3 blocks/CU (LDS 3x34.3=103KB < 160KB, 24 waves/
// CU = 75% cap). 1.5x the TLP of R15's 2-block tier to cover barrier-drain
// and L1-return stalls.
// Structure (best=380us, R15): x staged once per block into LDS (separate
// 128 B/cyc port) via global_load_lds, double-buffered 2-chunk groups,
// 9 barriers; W via L1 (4 loads/wave/chunk); stats from staged x; parallel
// scalar tail; column-sliced phase B.
//
// out = x + LN(c*x)*gamma + beta; LN(c*x) collapses to
//   normed = gamma*(alpha*x - alpha*mu) + beta,
//   alpha = c*rsqrt(c^2*var + 1e-5), mu/var = plain row stats of x.

constexpr int Dh     = 4096;
constexpr int Ph     = 16;
constexpr int NPL    = 32;
constexpr int CHUNK  = 256;           // 64 lanes * 4 floats
constexpr int GCH    = 2;             // chunks per group (512 cols)
constexpr int NGRP   = Dh / (CHUNK * GCH);   // 8
constexpr int RPB    = 8;             // rows per block
constexpr int NW     = 8;             // waves per block
constexpr int PPW    = NPL / NW;      // 4 planes per wave
constexpr int BLOCK  = 64 * NW;       // 512

__device__ __forceinline__ void stage_chunk(const float* src, float* ldsdst) {
    __builtin_amdgcn_global_load_lds(
        (const __attribute__((address_space(1))) void*)src,
        (__attribute__((address_space(3))) void*)ldsdst, 16, 0, 0);
}

__global__ __launch_bounds__(BLOCK, 6)
void phase_fused(const float* __restrict__ x,
                 const float* __restrict__ Wr,
                 const float* __restrict__ br,
                 const float* __restrict__ Wo,
                 const float* __restrict__ bo,
                 const float* __restrict__ gamma,
                 const float* __restrict__ beta,
                 float* __restrict__ out)
{
    __shared__ float x_lds[2][GCH][RPB][CHUNK];   // 32 KB double buffer
    __shared__ float dots_lds[RPB][NPL];
    __shared__ float stats_lds[RPB][2];
    __shared__ float scale_lds[RPB][2];

    const int t    = threadIdx.x;
    const int wv   = t >> 6;
    const int lane = t & 63;
    const size_t rowbase = (size_t)blockIdx.x * RPB;

    // Per-wave W pointers (lane offset folded in).
    const float* wrow[PPW];
#pragma unroll
    for (int p = 0; p < PPW; ++p) {
        const int q = wv * PPW + p;
        wrow[p] = ((q < Ph) ? (Wr + (size_t)q * Dh) : (Wo + (size_t)(q - Ph) * Dh))
                  + lane * 4;
    }
    // Wave wv stages row wv; global src per-lane, LDS dst wave-uniform linear.
    const float* xsrc = x + (rowbase + wv) * (size_t)Dh + lane * 4;

    float acc[RPB][PPW];
#pragma unroll
    for (int r = 0; r < RPB; ++r)
#pragma unroll
        for (int p = 0; p < PPW; ++p) acc[r][p] = 0.f;
    float sx = 0.f, sxx = 0.f;

    // Stage one 512-col group (2 chunks) of this wave's row into buf.
    auto stage_group = [&](int g, int buf) {
#pragma unroll
        for (int k = 0; k < GCH; ++k)
            stage_chunk(xsrc + (size_t)(g * GCH + k) * CHUNK,
                        &x_lds[buf][k][wv][0]);
    };

    // Compute one group from buf (const buf at every call site).
    auto compute_group = [&](int g, int buf) {
#pragma unroll 1
        for (int k = 0; k < GCH; ++k) {
            const int off = (g * GCH + k) * CHUNK;
            float4 w4[PPW];
#pragma unroll
            for (int p = 0; p < PPW; ++p)
                w4[p] = *(const float4*)(wrow[p] + off);
            float4 x4[RPB];
#pragma unroll
            for (int r = 0; r < RPB; ++r)
                x4[r] = *(const float4*)(&x_lds[buf][k][r][lane * 4]);

#pragma unroll
            for (int r = 0; r < RPB; ++r) {
                if (r == wv) {   // wave-uniform; static indices
                    sx  += x4[r].x + x4[r].y + x4[r].z + x4[r].w;
                    sxx += x4[r].x*x4[r].x + x4[r].y*x4[r].y
                         + x4[r].z*x4[r].z + x4[r].w*x4[r].w;
                }
#pragma unroll
                for (int p = 0; p < PPW; ++p)
                    acc[r][p] += x4[r].x*w4[p].x + x4[r].y*w4[p].y
                               + x4[r].z*w4[p].z + x4[r].w*w4[p].w;
            }
        }
    };

    // Software pipeline, 9 barriers. compute(g) reads buf g&1 while
    // stage(g+1) fills the other; the vmcnt(0) drain at each barrier is
    // covered by group compute + 2 co-resident blocks' progress.
    stage_group(0, 0);
    __syncthreads();
    stage_group(1, 1); compute_group(0, 0);
    __syncthreads();
    stage_group(2, 0); compute_group(1, 1);
    __syncthreads();
    stage_group(3, 1); compute_group(2, 0);
    __syncthreads();
    stage_group(4, 0); compute_group(3, 1);
    __syncthreads();
    stage_group(5, 1); compute_group(4, 0);
    __syncthreads();
    stage_group(6, 0); compute_group(5, 1);
    __syncthreads();
    stage_group(7, 1); compute_group(6, 0);
    __syncthreads();
    compute_group(7, 1);

    // Butterfly-reduce accumulators across the 64 lanes.
#pragma unroll
    for (int r = 0; r < RPB; ++r)
#pragma unroll
        for (int p = 0; p < PPW; ++p) {
            float v = acc[r][p];
#pragma unroll
            for (int m = 1; m < 64; m <<= 1) v += __shfl_xor(v, m, 64);
            if (lane == 0) dots_lds[r][wv * PPW + p] = v;
        }
#pragma unroll
    for (int m = 1; m < 64; m <<= 1) {
        sx  += __shfl_xor(sx, m, 64);
        sxx += __shfl_xor(sxx, m, 64);
    }
    if (lane == 0) { stats_lds[wv][0] = sx; stats_lds[wv][1] = sxx; }
    __syncthreads();

    // Scalar phase, parallel over (row, plane): 128 threads, 16-lane reduce.
    if (t < RPB * Ph) {
        const int r = t >> 4, p = t & 15;
        float d1 = dots_lds[r][p]      + br[p];
        float d2 = dots_lds[r][Ph + p] + bo[p];
        float cd = cosf((tanhf(d1) - tanhf(d2)) * 3.14159265358979323846f);
#pragma unroll
        for (int m = 1; m < 16; m <<= 1) cd += __shfl_xor(cd, m, 16);
        if (p == 0) {
            float s    = cd;
            float gain = log1pf(expf(s * (1.f / Ph) + 0.5f));  // softplus
            float cm   = s * gain * (1.f / Ph);
            float mu   = stats_lds[r][0] * (1.f / Dh);
            float var  = stats_lds[r][1] * (1.f / Dh) - mu * mu;
            var = fmaxf(var, 0.f);
            float rstd  = rsqrtf(cm * cm * var + 1e-5f);
            float alpha = cm * rstd;
            scale_lds[r][0] = alpha;
            scale_lds[r][1] = alpha * mu;
        }
    }
    __syncthreads();

    // Phase B, column-sliced: wave wv owns cols [wv*512, wv*512+512);
    // gamma/beta loaded ONCE per wave, reused across all 8 rows. x re-read
    // is L2-hot (FETCH_SIZE ~= x-once at HBM every round).
    {
        const int col0 = wv * 512 + lane * 4;
        const float4 g4a = *(const float4*)(gamma + col0);
        const float4 g4b = *(const float4*)(gamma + col0 + 256);
        const float4 b4a = *(const float4*)(beta  + col0);
        const float4 b4b = *(const float4*)(beta  + col0 + 256);
#pragma unroll
        for (int r = 0; r < RPB; ++r) {
            const float alpha = scale_lds[r][0];
            const float am    = scale_lds[r][1];
            const float* xr  = x   + (rowbase + r) * (size_t)Dh;
            float*       orw = out + (rowbase + r) * (size_t)Dh;
            float4 xa = *(const float4*)(xr + col0);
            float4 xb = *(const float4*)(xr + col0 + 256);
            float4 oa, ob;
            oa.x = xa.x + g4a.x * (alpha * xa.x - am) + b4a.x;
            oa.y = xa.y + g4a.y * (alpha * xa.y - am) + b4a.y;
            oa.z = xa.z + g4a.z * (alpha * xa.z - am) + b4a.z;
            oa.w = xa.w + g4a.w * (alpha * xa.w - am) + b4a.w;
            ob.x = xb.x + g4b.x * (alpha * xb.x - am) + b4b.x;
            ob.y = xb.y + g4b.y * (alpha * xb.y - am) + b4b.y;
            ob.z = xb.z + g4b.z * (alpha * xb.z - am) + b4b.z;
            ob.w = xb.w + g4b.w * (alpha * xb.w - am) + b4b.w;
            *(float4*)(orw + col0)       = oa;
            *(float4*)(orw + col0 + 256) = ob;
        }
    }
}

extern "C" void kernel_launch(void* const* d_in, const int* in_sizes, int n_in,
                              void* d_out, int out_size, void* d_ws, size_t ws_size,
                              hipStream_t stream)
{
    const float* x     = (const float*)d_in[0];
    const float* Wr    = (const float*)d_in[1];
    const float* br    = (const float*)d_in[2];
    const float* Wo    = (const float*)d_in[3];
    const float* bo    = (const float*)d_in[4];
    const float* gamma = (const float*)d_in[5];
    const float* beta  = (const float*)d_in[6];
    float* out = (float*)d_out;

    const int B = in_sizes[0] / Dh;       // 32768
    dim3 grid(B / RPB);                   // 4096 blocks
    phase_fused<<<grid, BLOCK, 0, stream>>>(x, Wr, br, Wo, bo, gamma, beta, out);
}

// Round 18
// 407.722 us; speedup vs baseline: 5.9261x; 4.0162x over previous
//
#include <hip/hip_runtime.h>
#include <math.h>

// PhaseRefinement fused kernel, v18: ALL operands through LDS.
// Ledger: R16/R17 established blocks/CU = floor(256/(wavesPerSIMDperBlock *
// VGPR)); our acc[8][4]=32-reg body pins V=64 -> 16 waves/CU hard ceiling.
// R15 (380us, best) has per-wave duty = VALUBusy/wavesPerSIMD = 40/3.5 = 11%:
// waves idle 89%, dominated by the 4 W global loads sitting in the FMA
// dependency chain every chunk (~300-600cyc L2 latency, nothing to overlap)
// + barrier convoys. W register ping-pong needs +16 regs -> occupancy cliff.
// Fix: stage W in LDS as well. Compute = pure {ds_read -> FMA}; no global
// latency in any dependency chain. W[32][256]=32KB single-buffered +
// x[8][256]=8KB: ~41KB -> 2 blocks resident. 40 stage-calls of 1KB = 5/wave.
// 2 barriers/chunk (reads-done -> stage -> landed); the exposed stage window
// is covered by the anti-phased co-resident block whose compute is now
// stall-free. LDS row indices are compile-time -> addressing VALU ~0.
//
// out = x + LN(c*x)*gamma + beta; LN(c*x) collapses to
//   normed = gamma*(alpha*x - alpha*mu) + beta,
//   alpha = c*rsqrt(c^2*var + 1e-5), mu/var = plain row stats of x.

constexpr int Dh     = 4096;
constexpr int Ph     = 16;
constexpr int NPL    = 32;
constexpr int CHUNK  = 256;          // 64 lanes * 4 floats
constexpr int NCHUNK = Dh / CHUNK;   // 16
constexpr int RPB    = 8;            // rows per block
constexpr int NW     = 8;            // waves per block
constexpr int PPW    = NPL / NW;     // 4 planes per wave
constexpr int BLOCK  = 64 * NW;      // 512

__device__ __forceinline__ void stage_1kb(const float* src, float* ldsdst) {
    __builtin_amdgcn_global_load_lds(
        (const __attribute__((address_space(1))) void*)src,
        (__attribute__((address_space(3))) void*)ldsdst, 16, 0, 0);
}

__global__ __launch_bounds__(BLOCK, 4)   // cap V at 64: the 2-block tier
void phase_fused(const float* __restrict__ x,
                 const float* __restrict__ Wr,
                 const float* __restrict__ br,
                 const float* __restrict__ Wo,
                 const float* __restrict__ bo,
                 const float* __restrict__ gamma,
                 const float* __restrict__ beta,
                 float* __restrict__ out)
{
    __shared__ float W_lds[NPL][CHUNK];   // 32 KB, single-buffered
    __shared__ float x_lds[RPB][CHUNK];   // 8 KB, single-buffered
    // Tail arrays reuse W_lds after the main loop (dead by then).
    float* const dots_f  = &W_lds[0][0];          // [RPB*NPL] = 256 floats
    float* const stats_f = &W_lds[1][0];          // sx[8], sxx[8]
    float* const scale_f = &W_lds[1][16];         // alpha[8], am[8]

    const int t    = threadIdx.x;
    const int wv   = t >> 6;
    const int lane = t & 63;
    const size_t rowbase = (size_t)blockIdx.x * RPB;

    // This wave's 5 stage sources: W planes {wv, wv+8, wv+16, wv+24} + x row wv.
    const float* wsrc[4];
    int          wdst[4];
#pragma unroll
    for (int j = 0; j < 4; ++j) {
        const int q = wv + j * 8;
        wsrc[j] = ((q < Ph) ? (Wr + (size_t)q * Dh) : (Wo + (size_t)(q - Ph) * Dh))
                  + lane * 4;
        wdst[j] = q;
    }
    const float* xsrc = x + (rowbase + wv) * (size_t)Dh + lane * 4;

    // This wave's W read base (wv resolved once; row offsets compile-time).
    const float* wbase = &W_lds[wv * PPW][0];

    float acc[RPB][PPW];
#pragma unroll
    for (int r = 0; r < RPB; ++r)
#pragma unroll
        for (int p = 0; p < PPW; ++p) acc[r][p] = 0.f;
    float sx = 0.f, sxx = 0.f;

    auto stage_all = [&](int c) {
#pragma unroll
        for (int j = 0; j < 4; ++j)
            stage_1kb(wsrc[j] + (size_t)c * CHUNK, &W_lds[wdst[j]][0]);
        stage_1kb(xsrc + (size_t)c * CHUNK, &x_lds[wv][0]);
    };

    stage_all(0);
    __syncthreads();                       // stage(0) landed

#pragma unroll 1
    for (int c = 0; c < NCHUNK; ++c) {
        // Pure-LDS compute: 12 ds_read_b128 (conflict-free, short latency),
        // 128 FMA. No global load in any dependency chain.
        float4 w4[PPW];
#pragma unroll
        for (int p = 0; p < PPW; ++p)
            w4[p] = *(const float4*)(wbase + p * CHUNK + lane * 4);
        float4 x4[RPB];
#pragma unroll
        for (int r = 0; r < RPB; ++r)
            x4[r] = *(const float4*)(&x_lds[r][lane * 4]);

#pragma unroll
        for (int r = 0; r < RPB; ++r) {
            if (r == wv) {   // wave-uniform; static indices
                sx  += x4[r].x + x4[r].y + x4[r].z + x4[r].w;
                sxx += x4[r].x*x4[r].x + x4[r].y*x4[r].y
                     + x4[r].z*x4[r].z + x4[r].w*x4[r].w;
            }
#pragma unroll
            for (int p = 0; p < PPW; ++p)
                acc[r][p] += x4[r].x*w4[p].x + x4[r].y*w4[p].y
                           + x4[r].z*w4[p].z + x4[r].w*w4[p].w;
        }

        __syncthreads();                   // all reads of chunk c done
        if (c + 1 < NCHUNK) {
            stage_all(c + 1);              // bulk stage, no consumers here
            __syncthreads();               // drain: stage(c+1) landed
        }
    }
    __syncthreads();                       // W_lds now dead; reuse for tail

    // Butterfly-reduce accumulators across the 64 lanes.
#pragma unroll
    for (int r = 0; r < RPB; ++r)
#pragma unroll
        for (int p = 0; p < PPW; ++p) {
            float v = acc[r][p];
#pragma unroll
            for (int m = 1; m < 64; m <<= 1) v += __shfl_xor(v, m, 64);
            if (lane == 0) dots_f[r * NPL + wv * PPW + p] = v;
        }
#pragma unroll
    for (int m = 1; m < 64; m <<= 1) {
        sx  += __shfl_xor(sx, m, 64);
        sxx += __shfl_xor(sxx, m, 64);
    }
    if (lane == 0) { stats_f[wv] = sx; stats_f[8 + wv] = sxx; }
    __syncthreads();

    // Scalar phase, parallel over (row, plane): 128 threads, 16-lane reduce.
    if (t < RPB * Ph) {
        const int r = t >> 4, p = t & 15;
        float d1 = dots_f[r * NPL + p]      + br[p];
        float d2 = dots_f[r * NPL + Ph + p] + bo[p];
        float cd = cosf((tanhf(d1) - tanhf(d2)) * 3.14159265358979323846f);
#pragma unroll
        for (int m = 1; m < 16; m <<= 1) cd += __shfl_xor(cd, m, 16);
        if (p == 0) {
            float s    = cd;
            float gain = log1pf(expf(s * (1.f / Ph) + 0.5f));  // softplus
            float cm   = s * gain * (1.f / Ph);
            float mu   = stats_f[r] * (1.f / Dh);
            float var  = stats_f[8 + r] * (1.f / Dh) - mu * mu;
            var = fmaxf(var, 0.f);
            float rstd  = rsqrtf(cm * cm * var + 1e-5f);
            float alpha = cm * rstd;
            scale_f[r]     = alpha;
            scale_f[8 + r] = alpha * mu;
        }
    }
    __syncthreads();

    // Phase B, column-sliced: wave wv owns cols [wv*512, wv*512+512);
    // gamma/beta loaded ONCE per wave, reused across all 8 rows. x re-read
    // is L2-hot (FETCH_SIZE ~= x-once at HBM every round).
    {
        const int col0 = wv * 512 + lane * 4;
        const float4 g4a = *(const float4*)(gamma + col0);
        const float4 g4b = *(const float4*)(gamma + col0 + 256);
        const float4 b4a = *(const float4*)(beta  + col0);
        const float4 b4b = *(const float4*)(beta  + col0 + 256);
#pragma unroll
        for (int r = 0; r < RPB; ++r) {
            const float alpha = scale_f[r];
            const float am    = scale_f[8 + r];
            const float* xr  = x   + (rowbase + r) * (size_t)Dh;
            float*       orw = out + (rowbase + r) * (size_t)Dh;
            float4 xa = *(const float4*)(xr + col0);
            float4 xb = *(const float4*)(xr + col0 + 256);
            float4 oa, ob;
            oa.x = xa.x + g4a.x * (alpha * xa.x - am) + b4a.x;
            oa.y = xa.y + g4a.y * (alpha * xa.y - am) + b4a.y;
            oa.z = xa.z + g4a.z * (alpha * xa.z - am) + b4a.z;
            oa.w = xa.w + g4a.w * (alpha * xa.w - am) + b4a.w;
            ob.x = xb.x + g4b.x * (alpha * xb.x - am) + b4b.x;
            ob.y = xb.y + g4b.y * (alpha * xb.y - am) + b4b.y;
            ob.z = xb.z + g4b.z * (alpha * xb.z - am) + b4b.z;
            ob.w = xb.w + g4b.w * (alpha * xb.w - am) + b4b.w;
            *(float4*)(orw + col0)       = oa;
            *(float4*)(orw + col0 + 256) = ob;
        }
    }
}

extern "C" void kernel_launch(void* const* d_in, const int* in_sizes, int n_in,
                              void* d_out, int out_size, void* d_ws, size_t ws_size,
                              hipStream_t stream)
{
    const float* x     = (const float*)d_in[0];
    const float* Wr    = (const float*)d_in[1];
    const float* br    = (const float*)d_in[2];
    const float* Wo    = (const float*)d_in[3];
    const float* bo    = (const float*)d_in[4];
    const float* gamma = (const float*)d_in[5];
    const float* beta  = (const float*)d_in[6];
    float* out = (float*)d_out;

    const int B = in_sizes[0] / Dh;       // 32768
    dim3 grid(B / RPB);                   // 4096 blocks
    phase_fused<<<grid, BLOCK, 0, stream>>>(x, Wr, br, Wo, bo, gamma, beta, out);
}